// Round 2
// baseline (588.094 us; speedup 1.0000x reference)
//
#include <hip/hip_runtime.h>
#include <hip/hip_bf16.h>

#define NHEADS 16
#define DIN    1024
#define DOUT   64
#define NTOK   2048

// ---------------------------------------------------------------------------
// Kernel 1: fused Q/K/V projection (fp32 in, fp32 out).
// grid (NTOK/64, NHEADS, 3); block 256. 64x64 output tile, BK=16, 4x4 micro.
// Q/K/V stored fp32 in workspace as [h][n][e].
// ---------------------------------------------------------------------------
__global__ __launch_bounds__(256) void qkv_proj_kernel(
    const float* __restrict__ x,    // [NTOK][DIN]
    const float* __restrict__ qw,   // [H][DIN][DOUT]
    const float* __restrict__ kw,
    const float* __restrict__ vw,
    float* __restrict__ Q, float* __restrict__ K, float* __restrict__ V)
{
    const int n0 = blockIdx.x * 64;
    const int h  = blockIdx.y;
    const int wh = blockIdx.z;
    const float* W = (wh == 0 ? qw : wh == 1 ? kw : vw) + h * (DIN * DOUT);
    float* O = (wh == 0 ? Q : wh == 1 ? K : V) + h * (NTOK * DOUT);

    __shared__ float xs[16][68];   // xs[k][n]  (x tile, transposed)
    __shared__ float ws[16][68];   // ws[k][e]

    const int t  = threadIdx.x;
    const int tr = t >> 4;             // 0..15 -> output rows 4*tr..
    const int tc = t & 15;             // 0..15 -> output cols 4*tc..
    const int lx_row = t >> 2;         // 0..63
    const int lx_col = (t & 3) * 4;    // 0,4,8,12
    const int lw_row = t >> 4;         // 0..15
    const int lw_col = (t & 15) * 4;   // 0..60

    float acc[4][4] = {{0.f, 0.f, 0.f, 0.f}};

    for (int k0 = 0; k0 < DIN; k0 += 16) {
        const float4 xv = *(const float4*)&x[(n0 + lx_row) * DIN + k0 + lx_col];
        const float4 wv = *(const float4*)&W[(k0 + lw_row) * DOUT + lw_col];
        __syncthreads();
        xs[lx_col + 0][lx_row] = xv.x;
        xs[lx_col + 1][lx_row] = xv.y;
        xs[lx_col + 2][lx_row] = xv.z;
        xs[lx_col + 3][lx_row] = xv.w;
        *(float4*)&ws[lw_row][lw_col] = wv;
        __syncthreads();
        #pragma unroll
        for (int k = 0; k < 16; ++k) {
            const float4 a = *(const float4*)&xs[k][tr * 4];
            const float4 b = *(const float4*)&ws[k][tc * 4];
            const float av[4] = {a.x, a.y, a.z, a.w};
            const float bv[4] = {b.x, b.y, b.z, b.w};
            #pragma unroll
            for (int i = 0; i < 4; ++i)
                #pragma unroll
                for (int j = 0; j < 4; ++j)
                    acc[i][j] += av[i] * bv[j];
        }
    }
    #pragma unroll
    for (int i = 0; i < 4; ++i) {
        *(float4*)&O[(n0 + tr * 4 + i) * DOUT + tc * 4] =
            make_float4(acc[i][0], acc[i][1], acc[i][2], acc[i][3]);
    }
}

// ---------------------------------------------------------------------------
// Kernel 2: flash-style fused attention per head.
// grid (NTOK/64, NHEADS); block 256. 64 Q-rows per block; iterate 64-key tiles.
// ctx written pre-concatenated: ctx[n][h*64+e] (fp32 in workspace).
// ---------------------------------------------------------------------------
__global__ __launch_bounds__(256) void attn_kernel(
    const float* __restrict__ Q, const float* __restrict__ K,
    const float* __restrict__ V, float* __restrict__ ctx)
{
    const int r0 = blockIdx.x * 64;
    const int h  = blockIdx.y;
    const float* Qh = Q + h * (NTOK * DOUT);
    const float* Kh = K + h * (NTOK * DOUT);
    const float* Vh = V + h * (NTOK * DOUT);

    __shared__ float Qt[64][68];    // Qt[e][r]
    __shared__ float KtPt[64][68];  // Kt[e][c], later aliased as Pt[c][r]
    __shared__ float Vs[64][68];    // Vs[c][e]

    const int t  = threadIdx.x;
    const int tr = t >> 4;
    const int tc = t & 15;
    const int lrow = t >> 2;         // 0..63
    const int lcb  = (t & 3) * 16;   // 0,16,32,48

    // load Q tile transposed (once)
    #pragma unroll
    for (int it = 0; it < 4; ++it) {
        const int col = lcb + it * 4;
        const float4 qv = *(const float4*)&Qh[(r0 + lrow) * DOUT + col];
        Qt[col + 0][lrow] = qv.x;
        Qt[col + 1][lrow] = qv.y;
        Qt[col + 2][lrow] = qv.z;
        Qt[col + 3][lrow] = qv.w;
    }

    float m_i[4], l_i[4], o_acc[4][4];
    #pragma unroll
    for (int i = 0; i < 4; ++i) {
        m_i[i] = -3.0e38f;
        l_i[i] = 0.f;
        #pragma unroll
        for (int j = 0; j < 4; ++j) o_acc[i][j] = 0.f;
    }

    for (int m0 = 0; m0 < NTOK; m0 += 64) {
        __syncthreads();  // previous tile's Pt/Vs reads complete
        #pragma unroll
        for (int it = 0; it < 4; ++it) {
            const int col = lcb + it * 4;
            const float4 kv = *(const float4*)&Kh[(m0 + lrow) * DOUT + col];
            KtPt[col + 0][lrow] = kv.x;
            KtPt[col + 1][lrow] = kv.y;
            KtPt[col + 2][lrow] = kv.z;
            KtPt[col + 3][lrow] = kv.w;
            *(float4*)&Vs[lrow][col] = *(const float4*)&Vh[(m0 + lrow) * DOUT + col];
        }
        __syncthreads();

        // S = Q K^T (4x4 micro-tile per thread)
        float s[4][4] = {{0.f, 0.f, 0.f, 0.f}};
        #pragma unroll 8
        for (int e = 0; e < 64; ++e) {
            const float4 a = *(const float4*)&Qt[e][tr * 4];
            const float4 b = *(const float4*)&KtPt[e][tc * 4];
            const float av[4] = {a.x, a.y, a.z, a.w};
            const float bv[4] = {b.x, b.y, b.z, b.w};
            #pragma unroll
            for (int i = 0; i < 4; ++i)
                #pragma unroll
                for (int j = 0; j < 4; ++j)
                    s[i][j] += av[i] * bv[j];
        }

        // online softmax (per row: reduce across the 16 lanes sharing tr)
        #pragma unroll
        for (int i = 0; i < 4; ++i) {
            #pragma unroll
            for (int j = 0; j < 4; ++j) s[i][j] *= 0.125f;  // 1/sqrt(64)
            float mx = fmaxf(fmaxf(s[i][0], s[i][1]), fmaxf(s[i][2], s[i][3]));
            mx = fmaxf(mx, __shfl_xor(mx, 1));
            mx = fmaxf(mx, __shfl_xor(mx, 2));
            mx = fmaxf(mx, __shfl_xor(mx, 4));
            mx = fmaxf(mx, __shfl_xor(mx, 8));
            const float mn = fmaxf(m_i[i], mx);
            const float alpha = __expf(m_i[i] - mn);
            m_i[i] = mn;
            float sum = 0.f;
            #pragma unroll
            for (int j = 0; j < 4; ++j) {
                s[i][j] = __expf(s[i][j] - mn);
                sum += s[i][j];
            }
            sum += __shfl_xor(sum, 1);
            sum += __shfl_xor(sum, 2);
            sum += __shfl_xor(sum, 4);
            sum += __shfl_xor(sum, 8);
            l_i[i] = l_i[i] * alpha + sum;
            #pragma unroll
            for (int j = 0; j < 4; ++j) o_acc[i][j] *= alpha;
        }

        __syncthreads();  // all Kt reads done; safe to overwrite with Pt
        #pragma unroll
        for (int i = 0; i < 4; ++i)
            #pragma unroll
            for (int j = 0; j < 4; ++j)
                KtPt[tc * 4 + j][tr * 4 + i] = s[i][j];  // Pt[c][r]
        __syncthreads();

        // O += P V
        #pragma unroll 8
        for (int c = 0; c < 64; ++c) {
            const float4 p = *(const float4*)&KtPt[c][tr * 4];
            const float4 v = *(const float4*)&Vs[c][tc * 4];
            const float pv[4] = {p.x, p.y, p.z, p.w};
            const float vv[4] = {v.x, v.y, v.z, v.w};
            #pragma unroll
            for (int i = 0; i < 4; ++i)
                #pragma unroll
                for (int j = 0; j < 4; ++j)
                    o_acc[i][j] += pv[i] * vv[j];
        }
    }

    #pragma unroll
    for (int i = 0; i < 4; ++i) {
        const float inv = 1.f / l_i[i];
        *(float4*)&ctx[(r0 + tr * 4 + i) * DIN + h * DOUT + tc * 4] =
            make_float4(o_acc[i][0] * inv, o_acc[i][1] * inv,
                        o_acc[i][2] * inv, o_acc[i][3] * inv);
    }
}

// ---------------------------------------------------------------------------
// Kernel 3: output projection out = ctx @ o_proj (fp32 in, fp32 out).
// grid (NTOK/64, DIN/64); block 256.
// ---------------------------------------------------------------------------
__global__ __launch_bounds__(256) void out_proj_kernel(
    const float* __restrict__ C, const float* __restrict__ Wo,
    float* __restrict__ out)
{
    const int n0 = blockIdx.x * 64;
    const int c0 = blockIdx.y * 64;

    __shared__ float as[16][68];   // as[k][n]
    __shared__ float bs[16][68];   // bs[k][e]

    const int t  = threadIdx.x;
    const int tr = t >> 4;
    const int tc = t & 15;
    const int la_row = t >> 2;
    const int la_col = (t & 3) * 4;
    const int lb_row = t >> 4;
    const int lb_col = (t & 15) * 4;

    float acc[4][4] = {{0.f, 0.f, 0.f, 0.f}};

    for (int k0 = 0; k0 < DIN; k0 += 16) {
        const float4 av = *(const float4*)&C[(n0 + la_row) * DIN + k0 + la_col];
        const float4 bv = *(const float4*)&Wo[(k0 + lb_row) * DIN + c0 + lb_col];
        __syncthreads();
        as[la_col + 0][la_row] = av.x;
        as[la_col + 1][la_row] = av.y;
        as[la_col + 2][la_row] = av.z;
        as[la_col + 3][la_row] = av.w;
        *(float4*)&bs[lb_row][lb_col] = bv;
        __syncthreads();
        #pragma unroll
        for (int k = 0; k < 16; ++k) {
            const float4 a = *(const float4*)&as[k][tr * 4];
            const float4 b = *(const float4*)&bs[k][tc * 4];
            const float avr[4] = {a.x, a.y, a.z, a.w};
            const float bvr[4] = {b.x, b.y, b.z, b.w};
            #pragma unroll
            for (int i = 0; i < 4; ++i)
                #pragma unroll
                for (int j = 0; j < 4; ++j)
                    acc[i][j] += avr[i] * bvr[j];
        }
    }
    #pragma unroll
    for (int i = 0; i < 4; ++i) {
        *(float4*)&out[(n0 + tr * 4 + i) * DIN + c0 + tc * 4] =
            make_float4(acc[i][0], acc[i][1], acc[i][2], acc[i][3]);
    }
}

// ---------------------------------------------------------------------------
extern "C" void kernel_launch(void* const* d_in, const int* in_sizes, int n_in,
                              void* d_out, int out_size, void* d_ws, size_t ws_size,
                              hipStream_t stream) {
    const float* x  = (const float*)d_in[0];
    const float* qw = (const float*)d_in[1];
    const float* kw = (const float*)d_in[2];
    const float* vw = (const float*)d_in[3];
    const float* ow = (const float*)d_in[4];
    float* out = (float*)d_out;

    // workspace layout (fp32): Q | K | V | ctx  = 8 MiB each, 32 MiB total
    float* Q = (float*)d_ws;
    float* K = Q + (size_t)NHEADS * NTOK * DOUT;
    float* V = K + (size_t)NHEADS * NTOK * DOUT;
    float* C = V + (size_t)NHEADS * NTOK * DOUT;

    qkv_proj_kernel<<<dim3(NTOK / 64, NHEADS, 3), 256, 0, stream>>>(x, qw, kw, vw, Q, K, V);
    attn_kernel<<<dim3(NTOK / 64, NHEADS), 256, 0, stream>>>(Q, K, V, C);
    out_proj_kernel<<<dim3(NTOK / 64, DIN / 64), 256, 0, stream>>>(C, ow, out);
}

// Round 3
// 299.948 us; speedup vs baseline: 1.9607x; 1.9607x over previous
//
#include <hip/hip_runtime.h>

#define H 16
#define N 2048
#define E 64
#define D 1024

typedef __attribute__((ext_vector_type(8))) short bf16x8;
typedef __attribute__((ext_vector_type(4))) float f32x4;

__device__ __forceinline__ float bf2f(unsigned short u) {
    union { unsigned int i; float f; } v;
    v.i = ((unsigned int)u) << 16;
    return v.f;
}
__device__ __forceinline__ unsigned short f2bf(float f) {
    unsigned int u = __float_as_uint(f);
    return (unsigned short)((u + 0x7fffu + ((u >> 16) & 1u)) >> 16);
}
#define MFMA(a, b, c) __builtin_amdgcn_mfma_f32_16x16x32_bf16(a, b, c, 0, 0, 0)

// ---------------------------------------------------------------------------
// K1: x (fp32) -> xh, xl (bf16 hi/lo, same [n][d] layout)
// ---------------------------------------------------------------------------
__global__ __launch_bounds__(256) void convert_x_kernel(
    const float* __restrict__ x, unsigned short* __restrict__ xh,
    unsigned short* __restrict__ xl)
{
    const int i = (blockIdx.x * 256 + threadIdx.x) * 4;
    const float4 v = *(const float4*)&x[i];
    ushort4 hh, ll;
    hh.x = f2bf(v.x); ll.x = f2bf(v.x - bf2f(hh.x));
    hh.y = f2bf(v.y); ll.y = f2bf(v.y - bf2f(hh.y));
    hh.z = f2bf(v.z); ll.z = f2bf(v.z - bf2f(hh.z));
    hh.w = f2bf(v.w); ll.w = f2bf(v.w - bf2f(hh.w));
    *(ushort4*)&xh[i] = hh;
    *(ushort4*)&xl[i] = ll;
}

// ---------------------------------------------------------------------------
// K2: transpose-convert all weights.
//  q,k: W[h][d][e] -> Wt hi/lo [h][e][d]; v: single bf16 [h][e][d];
//  o:   Wo[d][c]   -> Wot hi/lo [c][d].
// 1024 blocks: [0,256)=q, [256,512)=k, [512,768)=v, [768,1024)=o.
// ---------------------------------------------------------------------------
__global__ __launch_bounds__(256) void convert_w_kernel(
    const float* __restrict__ qw, const float* __restrict__ kw,
    const float* __restrict__ vw, const float* __restrict__ ow,
    unsigned short* __restrict__ wqh, unsigned short* __restrict__ wql,
    unsigned short* __restrict__ wkh, unsigned short* __restrict__ wkl,
    unsigned short* __restrict__ wvt,
    unsigned short* __restrict__ woh, unsigned short* __restrict__ wol)
{
    __shared__ float ts[64][65];
    const int b = blockIdx.x;
    const int t = threadIdx.x;
    const float* src;
    int rs, dt, orow0;
    bool has_lo;
    unsigned short *dh, *dl;
    if (b < 768) {
        const int which = b >> 8, r = b & 255, h = r >> 4;
        dt = r & 15;
        src = (which == 0 ? qw : which == 1 ? kw : vw) + ((size_t)h * D + dt * 64) * E;
        rs = E;
        orow0 = h * 64;
        dh = which == 0 ? wqh : which == 1 ? wkh : wvt;
        dl = which == 0 ? wql : wkl;
        has_lo = (which < 2);
    } else {
        const int r = b - 768, ct = r >> 4;
        dt = r & 15;
        src = ow + (size_t)(dt * 64) * D + ct * 64;
        rs = D;
        orow0 = ct * 64;
        dh = woh; dl = wol; has_lo = true;
    }
    {
        const int row = t >> 2, cb = (t & 3) * 16;
        #pragma unroll
        for (int j = 0; j < 16; j += 4) {
            const float4 v = *(const float4*)&src[row * rs + cb + j];
            ts[row][cb + j + 0] = v.x;
            ts[row][cb + j + 1] = v.y;
            ts[row][cb + j + 2] = v.z;
            ts[row][cb + j + 3] = v.w;
        }
    }
    __syncthreads();
    {
        const int cl = t >> 2, dp = (t & 3) * 16;
        bf16x8 hv0, hv1, lv0, lv1;
        #pragma unroll
        for (int i = 0; i < 16; ++i) {
            const float f = ts[dp + i][cl];
            const unsigned short hh = f2bf(f);
            const unsigned short lo = f2bf(f - bf2f(hh));
            if (i < 8) { hv0[i] = (short)hh; lv0[i] = (short)lo; }
            else       { hv1[i - 8] = (short)hh; lv1[i - 8] = (short)lo; }
        }
        const size_t o = (size_t)(orow0 + cl) * D + dt * 64 + dp;
        *(bf16x8*)&dh[o] = hv0;
        *(bf16x8*)&dh[o + 8] = hv1;
        if (has_lo) {
            *(bf16x8*)&dl[o] = lv0;
            *(bf16x8*)&dl[o + 8] = lv1;
        }
    }
}

// ---------------------------------------------------------------------------
// K3: QKV projection via MFMA. grid (32 Mtiles, 16 heads, 3 which).
// q,k: 3-term split-bf16; v: single bf16.
// Outputs: Qh/Ql/Kh/Kl [h][n][e] (q scaled by 0.125); Vt [h][e][n].
// ---------------------------------------------------------------------------
__global__ __launch_bounds__(256) void qkv_proj_kernel(
    const unsigned short* __restrict__ xh, const unsigned short* __restrict__ xl,
    const unsigned short* __restrict__ wqh, const unsigned short* __restrict__ wql,
    const unsigned short* __restrict__ wkh, const unsigned short* __restrict__ wkl,
    const unsigned short* __restrict__ wvt,
    unsigned short* __restrict__ Qh, unsigned short* __restrict__ Ql,
    unsigned short* __restrict__ Kh, unsigned short* __restrict__ Kl,
    unsigned short* __restrict__ Vt)
{
    __shared__ unsigned short xsh[64][72], xsl[64][72], wsh[64][72], wsl[64][72];
    const int n0 = blockIdx.x * 64;
    const int h = blockIdx.y;
    const int which = blockIdx.z;
    const bool isv = (which == 2);
    const unsigned short* Wh = (which == 0 ? wqh : which == 1 ? wkh : wvt) + (size_t)h * 64 * D;
    const unsigned short* Wl = (which == 0 ? wql : wkl) + (size_t)h * 64 * D;

    const int t = threadIdx.x;
    const int lane = t & 63, wv = t >> 6, quad = lane >> 4, l15 = lane & 15;

    f32x4 acc[4];
    #pragma unroll
    for (int ct = 0; ct < 4; ++ct) acc[ct] = (f32x4){0.f, 0.f, 0.f, 0.f};

    for (int k0 = 0; k0 < D; k0 += 64) {
        #pragma unroll
        for (int rnd = 0; rnd < 2; ++rnd) {
            const int id = t + rnd * 256, row = id >> 3, cc = (id & 7) * 8;
            *(bf16x8*)&xsh[row][cc] = *(const bf16x8*)&xh[(size_t)(n0 + row) * D + k0 + cc];
            *(bf16x8*)&wsh[row][cc] = *(const bf16x8*)&Wh[(size_t)row * D + k0 + cc];
            if (!isv) {
                *(bf16x8*)&xsl[row][cc] = *(const bf16x8*)&xl[(size_t)(n0 + row) * D + k0 + cc];
                *(bf16x8*)&wsl[row][cc] = *(const bf16x8*)&Wl[(size_t)row * D + k0 + cc];
            }
        }
        __syncthreads();
        #pragma unroll
        for (int kw = 0; kw < 2; ++kw) {
            const bf16x8 ah = *(const bf16x8*)&xsh[wv * 16 + l15][kw * 32 + quad * 8];
            bf16x8 al;
            if (!isv) al = *(const bf16x8*)&xsl[wv * 16 + l15][kw * 32 + quad * 8];
            #pragma unroll
            for (int ct = 0; ct < 4; ++ct) {
                const bf16x8 bh = *(const bf16x8*)&wsh[ct * 16 + l15][kw * 32 + quad * 8];
                acc[ct] = MFMA(ah, bh, acc[ct]);
                if (!isv) {
                    const bf16x8 bl = *(const bf16x8*)&wsl[ct * 16 + l15][kw * 32 + quad * 8];
                    acc[ct] = MFMA(ah, bl, acc[ct]);
                    acc[ct] = MFMA(al, bh, acc[ct]);
                }
            }
        }
        __syncthreads();
    }

    if (!isv) {
        const float scale = (which == 0) ? 0.125f : 1.0f;  // fold 1/sqrt(64) into Q
        unsigned short* Oh = (which == 0) ? Qh : Kh;
        unsigned short* Ol = (which == 0) ? Ql : Kl;
        #pragma unroll
        for (int ct = 0; ct < 4; ++ct) {
            const int e = ct * 16 + l15;
            #pragma unroll
            for (int r = 0; r < 4; ++r) {
                const int n = n0 + wv * 16 + quad * 4 + r;
                const float val = acc[ct][r] * scale;
                const unsigned short hh = f2bf(val);
                Oh[((size_t)h * N + n) * E + e] = hh;
                Ol[((size_t)h * N + n) * E + e] = f2bf(val - bf2f(hh));
            }
        }
    } else {
        #pragma unroll
        for (int ct = 0; ct < 4; ++ct) {
            const int e = ct * 16 + l15;
            const int nb = n0 + wv * 16 + quad * 4;
            ushort4 pk;
            pk.x = f2bf(acc[ct][0]);
            pk.y = f2bf(acc[ct][1]);
            pk.z = f2bf(acc[ct][2]);
            pk.w = f2bf(acc[ct][3]);
            *(ushort4*)&Vt[((size_t)h * E + e) * N + nb] = pk;
        }
    }
}

// ---------------------------------------------------------------------------
// K4: flash attention via MFMA. grid (32 qtiles, 16 heads).
// S: 3-term split (Qh/Ql x Kh/Kl). P,V single bf16. O fp32 accum.
// ctx written pre-concatenated hi/lo: Ch/Cl [n][h*64+e].
// ---------------------------------------------------------------------------
__global__ __launch_bounds__(256) void attn_kernel(
    const unsigned short* __restrict__ Qh, const unsigned short* __restrict__ Ql,
    const unsigned short* __restrict__ Kh, const unsigned short* __restrict__ Kl,
    const unsigned short* __restrict__ Vt,
    unsigned short* __restrict__ Ch, unsigned short* __restrict__ Cl)
{
    __shared__ unsigned short ksh[64][72], ksl[64][72], vts[64][72], ps[64][72];
    const int r0 = blockIdx.x * 64, h = blockIdx.y;
    const int t = threadIdx.x, lane = t & 63, wv = t >> 6, quad = lane >> 4, l15 = lane & 15;

    // Q A-fragments: loop-invariant, load once from global.
    bf16x8 qfh[2], qfl[2];
    {
        const int n = r0 + wv * 16 + l15;
        const size_t base = ((size_t)h * N + n) * E;
        #pragma unroll
        for (int kw = 0; kw < 2; ++kw) {
            qfh[kw] = *(const bf16x8*)&Qh[base + kw * 32 + quad * 8];
            qfl[kw] = *(const bf16x8*)&Ql[base + kw * 32 + quad * 8];
        }
    }

    f32x4 oacc[4];
    #pragma unroll
    for (int ct = 0; ct < 4; ++ct) oacc[ct] = (f32x4){0.f, 0.f, 0.f, 0.f};
    float mrow[4] = {-1e30f, -1e30f, -1e30f, -1e30f};
    float lrow[4] = {0.f, 0.f, 0.f, 0.f};

    for (int m0 = 0; m0 < N; m0 += 64) {
        __syncthreads();  // prior-iter ksh/ksl/vts reads complete
        #pragma unroll
        for (int rnd = 0; rnd < 2; ++rnd) {
            const int id = t + rnd * 256, row = id >> 3, cc = (id & 7) * 8;
            *(bf16x8*)&ksh[row][cc] = *(const bf16x8*)&Kh[((size_t)h * N + m0 + row) * E + cc];
            *(bf16x8*)&ksl[row][cc] = *(const bf16x8*)&Kl[((size_t)h * N + m0 + row) * E + cc];
            *(bf16x8*)&vts[row][cc] = *(const bf16x8*)&Vt[((size_t)h * E + row) * N + m0 + cc];
        }
        __syncthreads();

        // S = Q K^T  (scaled: 0.125 folded into Q)
        f32x4 s[4];
        #pragma unroll
        for (int ct = 0; ct < 4; ++ct) s[ct] = (f32x4){0.f, 0.f, 0.f, 0.f};
        #pragma unroll
        for (int kw = 0; kw < 2; ++kw) {
            #pragma unroll
            for (int ct = 0; ct < 4; ++ct) {
                const bf16x8 bh = *(const bf16x8*)&ksh[ct * 16 + l15][kw * 32 + quad * 8];
                const bf16x8 bl = *(const bf16x8*)&ksl[ct * 16 + l15][kw * 32 + quad * 8];
                s[ct] = MFMA(qfh[kw], bh, s[ct]);
                s[ct] = MFMA(qfh[kw], bl, s[ct]);
                s[ct] = MFMA(qfl[kw], bh, s[ct]);
            }
        }

        // online softmax; row r of this wave's strip = wv*16 + quad*4 + r
        #pragma unroll
        for (int r = 0; r < 4; ++r) {
            float mx = fmaxf(fmaxf(s[0][r], s[1][r]), fmaxf(s[2][r], s[3][r]));
            mx = fmaxf(mx, __shfl_xor(mx, 1));
            mx = fmaxf(mx, __shfl_xor(mx, 2));
            mx = fmaxf(mx, __shfl_xor(mx, 4));
            mx = fmaxf(mx, __shfl_xor(mx, 8));
            const float mn = fmaxf(mrow[r], mx);
            const float alpha = __expf(mrow[r] - mn);
            mrow[r] = mn;
            float sum = 0.f;
            #pragma unroll
            for (int ct = 0; ct < 4; ++ct) {
                const float p = __expf(s[ct][r] - mn);
                s[ct][r] = p;
                sum += p;
            }
            sum += __shfl_xor(sum, 1);
            sum += __shfl_xor(sum, 2);
            sum += __shfl_xor(sum, 4);
            sum += __shfl_xor(sum, 8);
            lrow[r] = lrow[r] * alpha + sum;
            #pragma unroll
            for (int ct = 0; ct < 4; ++ct) oacc[ct][r] = oacc[ct][r] * alpha;
        }

        // P -> LDS (bf16). Wave-local round trip: each wave reads only its own
        // 16-row strip for the PV A-fragments, so no barrier needed here.
        #pragma unroll
        for (int ct = 0; ct < 4; ++ct)
            #pragma unroll
            for (int r = 0; r < 4; ++r)
                ps[wv * 16 + quad * 4 + r][ct * 16 + l15] = f2bf(s[ct][r]);

        // O += P V
        #pragma unroll
        for (int kw = 0; kw < 2; ++kw) {
            const bf16x8 pa = *(const bf16x8*)&ps[wv * 16 + l15][kw * 32 + quad * 8];
            #pragma unroll
            for (int ct = 0; ct < 4; ++ct) {
                const bf16x8 vb = *(const bf16x8*)&vts[ct * 16 + l15][kw * 32 + quad * 8];
                oacc[ct] = MFMA(pa, vb, oacc[ct]);
            }
        }
    }

    #pragma unroll
    for (int r = 0; r < 4; ++r) {
        const float inv = 1.f / lrow[r];
        const int n = r0 + wv * 16 + quad * 4 + r;
        #pragma unroll
        for (int ct = 0; ct < 4; ++ct) {
            const int c = h * 64 + ct * 16 + l15;
            const float val = oacc[ct][r] * inv;
            const unsigned short hh = f2bf(val);
            Ch[(size_t)n * D + c] = hh;
            Cl[(size_t)n * D + c] = f2bf(val - bf2f(hh));
        }
    }
}

// ---------------------------------------------------------------------------
// K5: out = ctx @ Wo via MFMA (3-term split). grid (32 Mtiles, 16 Ctiles).
// ---------------------------------------------------------------------------
__global__ __launch_bounds__(256) void out_proj_kernel(
    const unsigned short* __restrict__ Chh, const unsigned short* __restrict__ Cll,
    const unsigned short* __restrict__ Wh, const unsigned short* __restrict__ Wl,
    float* __restrict__ out)
{
    __shared__ unsigned short ash[64][72], asl[64][72], bsh[64][72], bsl[64][72];
    const int n0 = blockIdx.x * 64, c0 = blockIdx.y * 64;
    const int t = threadIdx.x, lane = t & 63, wv = t >> 6, quad = lane >> 4, l15 = lane & 15;

    f32x4 acc[4];
    #pragma unroll
    for (int ct = 0; ct < 4; ++ct) acc[ct] = (f32x4){0.f, 0.f, 0.f, 0.f};

    for (int k0 = 0; k0 < D; k0 += 64) {
        #pragma unroll
        for (int rnd = 0; rnd < 2; ++rnd) {
            const int id = t + rnd * 256, row = id >> 3, cc = (id & 7) * 8;
            *(bf16x8*)&ash[row][cc] = *(const bf16x8*)&Chh[(size_t)(n0 + row) * D + k0 + cc];
            *(bf16x8*)&asl[row][cc] = *(const bf16x8*)&Cll[(size_t)(n0 + row) * D + k0 + cc];
            *(bf16x8*)&bsh[row][cc] = *(const bf16x8*)&Wh[(size_t)(c0 + row) * D + k0 + cc];
            *(bf16x8*)&bsl[row][cc] = *(const bf16x8*)&Wl[(size_t)(c0 + row) * D + k0 + cc];
        }
        __syncthreads();
        #pragma unroll
        for (int kw = 0; kw < 2; ++kw) {
            const bf16x8 ah = *(const bf16x8*)&ash[wv * 16 + l15][kw * 32 + quad * 8];
            const bf16x8 al = *(const bf16x8*)&asl[wv * 16 + l15][kw * 32 + quad * 8];
            #pragma unroll
            for (int ct = 0; ct < 4; ++ct) {
                const bf16x8 bh = *(const bf16x8*)&bsh[ct * 16 + l15][kw * 32 + quad * 8];
                const bf16x8 bl = *(const bf16x8*)&bsl[ct * 16 + l15][kw * 32 + quad * 8];
                acc[ct] = MFMA(ah, bh, acc[ct]);
                acc[ct] = MFMA(ah, bl, acc[ct]);
                acc[ct] = MFMA(al, bh, acc[ct]);
            }
        }
        __syncthreads();
    }

    #pragma unroll
    for (int r = 0; r < 4; ++r) {
        const int n = n0 + wv * 16 + quad * 4 + r;
        #pragma unroll
        for (int ct = 0; ct < 4; ++ct)
            out[(size_t)n * D + c0 + ct * 16 + l15] = acc[ct][r];
    }
}

// ---------------------------------------------------------------------------
extern "C" void kernel_launch(void* const* d_in, const int* in_sizes, int n_in,
                              void* d_out, int out_size, void* d_ws, size_t ws_size,
                              hipStream_t stream) {
    const float* x  = (const float*)d_in[0];
    const float* qw = (const float*)d_in[1];
    const float* kw = (const float*)d_in[2];
    const float* vw = (const float*)d_in[3];
    const float* ow = (const float*)d_in[4];
    float* out = (float*)d_out;

    // workspace layout (bf16 shorts), total 21M shorts = 42 MB
    unsigned short* ws = (unsigned short*)d_ws;
    unsigned short* xh  = ws;                          // N*D = 2M
    unsigned short* xl  = xh  + (size_t)N * D;         // 2M
    unsigned short* wqh = xl  + (size_t)N * D;         // H*E*D = 1M
    unsigned short* wql = wqh + (size_t)H * E * D;
    unsigned short* wkh = wql + (size_t)H * E * D;
    unsigned short* wkl = wkh + (size_t)H * E * D;
    unsigned short* wvt = wkl + (size_t)H * E * D;
    unsigned short* woh = wvt + (size_t)H * E * D;     // D*D = 1M
    unsigned short* wol = woh + (size_t)D * D;
    unsigned short* Qh  = wol + (size_t)D * D;         // H*N*E = 2M
    unsigned short* Ql  = Qh  + (size_t)H * N * E;
    unsigned short* Kh  = Ql  + (size_t)H * N * E;
    unsigned short* Kl  = Kh  + (size_t)H * N * E;
    unsigned short* Vt  = Kl  + (size_t)H * N * E;     // [h][e][n]
    unsigned short* Ch  = xh;   // alias: x dead after qkv_proj
    unsigned short* Cl  = xl;

    convert_x_kernel<<<(N * D / 4) / 256, 256, 0, stream>>>(x, xh, xl);
    convert_w_kernel<<<1024, 256, 0, stream>>>(qw, kw, vw, ow,
                                               wqh, wql, wkh, wkl, wvt, woh, wol);
    qkv_proj_kernel<<<dim3(N / 64, H, 3), 256, 0, stream>>>(
        xh, xl, wqh, wql, wkh, wkl, wvt, Qh, Ql, Kh, Kl, Vt);
    attn_kernel<<<dim3(N / 64, H), 256, 0, stream>>>(Qh, Ql, Kh, Kl, Vt, Ch, Cl);
    out_proj_kernel<<<dim3(N / 64, D / 64), 256, 0, stream>>>(Ch, Cl, woh, wol, out);
}